// Round 1
// baseline (5470.031 us; speedup 1.0000x reference)
//
#include <hip/hip_runtime.h>
#include <math.h>

// Problem constants (from reference)
constexpr int D = 64;
constexpr int NU = 50000, NB = 20000, NI = 100000;
constexpr int BATCH = 2048, NCAND = 2, MAXDEG = 50, CORE_K = 3;
constexpr int PAD_IDX = NI;
constexpr int N_UB = NU + NB, N_UI = NU + NI, N_BI = NB + NI;

__device__ __forceinline__ float wave_sum64(float v) {
#pragma unroll
    for (int off = 32; off > 0; off >>= 1) v += __shfl_down(v, off);
    return v;  // valid in lane 0
}

// f_cur = acc = concat(feat_a, feat_b); float4-vectorized
__global__ void k_init(const float* __restrict__ fa, int na, int n,
                       const float* __restrict__ fb,
                       float* __restrict__ cur, float* __restrict__ acc) {
    size_t i = (size_t)blockIdx.x * blockDim.x + threadIdx.x;  // float4 index
    size_t total4 = (size_t)n * D / 4;
    if (i >= total4) return;
    size_t base = i * 4;
    size_t row = base >> 6;          // / D
    size_t off = base & 63;          // % D
    const float* src = (row < (size_t)na) ? (fa + row * D + off)
                                          : (fb + (row - na) * D + off);
    float4 v = *(const float4*)src;
    *(float4*)(cur + base) = v;
    *(float4*)(acc + base) = v;
}

// y[row] += val * x[col]  (COO scatter). 16 threads per edge, float4 gather,
// 4 scalar f32 HW atomics per thread.
__global__ void k_spmm(const int* __restrict__ row, const int* __restrict__ col,
                       const float* __restrict__ val,
                       const float* __restrict__ x, float* __restrict__ y,
                       int E) {
    size_t g = (size_t)blockIdx.x * blockDim.x + threadIdx.x;
    if (g >= (size_t)E * 16) return;
    int e = (int)(g >> 4);
    int q = (int)(g & 15);
    int r = row[e], c = col[e];
    float v = val[e];
    float4 xv = *(const float4*)(x + (size_t)c * D + q * 4);
    float* yp = y + (size_t)r * D + q * 4;
    unsafeAtomicAdd(yp + 0, v * xv.x);
    unsafeAtomicAdd(yp + 1, v * xv.y);
    unsafeAtomicAdd(yp + 2, v * xv.z);
    unsafeAtomicAdd(yp + 3, v * xv.w);
}

__global__ void k_add(float* __restrict__ acc, const float* __restrict__ nxt,
                      size_t n4) {
    size_t i = (size_t)blockIdx.x * blockDim.x + threadIdx.x;
    if (i >= n4) return;
    float4 a = ((const float4*)acc)[i];
    float4 b = ((const float4*)nxt)[i];
    a.x += b.x; a.y += b.y; a.z += b.z; a.w += b.w;
    ((float4*)acc)[i] = a;
}

__global__ void k_scale(float* __restrict__ acc, size_t n4, float s) {
    size_t i = (size_t)blockIdx.x * blockDim.x + threadIdx.x;
    if (i >= n4) return;
    float4 a = ((const float4*)acc)[i];
    a.x *= s; a.y *= s; a.z *= s; a.w *= s;
    ((float4*)acc)[i] = a;
}

// One wave (64 threads) per candidate pair n in [0, BATCH*NCAND).
// m_ub: [N_UB,D] = [UB_u ; UB_b], m_ui: [N_UI,D] = [UI_u ; UI_i],
// m_bi: [N_BI,D] = [BI_b ; BI_i]   (already scaled by 1/3 = mean over hops)
__global__ __launch_bounds__(64) void k_score(
    const int* __restrict__ users, const int* __restrict__ bundles,
    const int* __restrict__ bundle_items,
    const float* __restrict__ m_ub, const float* __restrict__ m_ui,
    const float* __restrict__ m_bi,
    const float* __restrict__ cw1, const float* __restrict__ cb1,
    const float* __restrict__ cw2, const float* __restrict__ cb2,
    const float* __restrict__ sw1, const float* __restrict__ sb1,
    const float* __restrict__ sw2, const float* __restrict__ sb2,
    float* __restrict__ scores) {
    const int n = blockIdx.x;
    const int t = threadIdx.x;  // 0..63 == feature dim
    const int u = users[n / NCAND];
    const int b = bundles[n];
    const int* bbi = bundle_items + (size_t)b * MAXDEG;

    __shared__ float s_items[MAXDEG][D];   // items_ui stash (12.8 KB)
    __shared__ float s_r[2][MAXDEG];       // r_UI, r_BI
    __shared__ float s_pi[MAXDEG];
    __shared__ int   s_top_i[CORE_K];
    __shared__ float s_top_p[CORE_K];
    __shared__ float s_syn[2 * D];
    __shared__ float s_h1[D];

    const float u_ui = m_ui[(size_t)u * D + t];          // UI_u[u]
    const float b_bi = m_bi[(size_t)b * D + t];          // BI_b[b]

    // --- 50 dot products against UI_i / BI_i item rows ---
    for (int m = 0; m < MAXDEG; ++m) {
        int it = bbi[m];
        float iu = 0.f, ib = 0.f;
        if (it != PAD_IDX) {
            iu = m_ui[(size_t)(NU + it) * D + t];
            ib = m_bi[(size_t)(NB + it) * D + t];
        }
        s_items[m][t] = iu;
        float pu = wave_sum64(u_ui * iu);
        float pb = wave_sum64(b_bi * ib);
        if (t == 0) { s_r[0][m] = pu; s_r[1][m] = pb; }
    }
    __syncthreads();

    // --- core MLP (2->32->1) per item, lanes 0..49 ---
    float logit = -INFINITY;
    if (t < MAXDEG) {
        float rU = s_r[0][t], rB = s_r[1][t];
        float acc = cb2[0];
#pragma unroll
        for (int j = 0; j < 32; ++j) {
            float h = fmaf(rU, cw1[j], fmaf(rB, cw1[32 + j], cb1[j]));
            h = fmaxf(h, 0.f);
            acc = fmaf(h, cw2[j], acc);
        }
        logit = (bbi[t] != PAD_IDX) ? acc : -INFINITY;
    }

    // --- softmax over 50 (lanes >= 50 contribute -inf / 0) ---
    float mx = logit;
#pragma unroll
    for (int off = 32; off > 0; off >>= 1) mx = fmaxf(mx, __shfl_down(mx, off));
    mx = __shfl(mx, 0);
    float ex = (t < MAXDEG) ? expf(logit - mx) : 0.f;
    float sm = wave_sum64(ex);
    sm = __shfl(sm, 0);
    if (t < MAXDEG) s_pi[t] = ex / sm;
    __syncthreads();

    // --- top-3 (serial on lane 0; strict > keeps lowest index on ties,
    //     matching jax.lax.top_k) ---
    if (t == 0) {
        bool used[MAXDEG];
        for (int m = 0; m < MAXDEG; ++m) used[m] = false;
        float tsum = 0.f;
        for (int k = 0; k < CORE_K; ++k) {
            float best = -1.f; int bidx = 0;
            for (int m = 0; m < MAXDEG; ++m)
                if (!used[m] && s_pi[m] > best) { best = s_pi[m]; bidx = m; }
            used[bidx] = true;
            s_top_i[k] = bidx;
            s_top_p[k] = best;
            tsum += best;
        }
        float inv = 1.f / (tsum + 1e-10f);
        for (int k = 0; k < CORE_K; ++k) s_top_p[k] *= inv;
    }
    __syncthreads();

    // --- h_core / h_fringe (per-lane feature dim t) ---
    float hcore = 0.f;
#pragma unroll
    for (int k = 0; k < CORE_K; ++k)
        hcore = fmaf(s_items[s_top_i[k]][t], s_top_p[k], hcore);

    float fsum = 0.f; int fcnt = 0;
    for (int m = 0; m < MAXDEG; ++m) {
        bool core = (m == s_top_i[0]) | (m == s_top_i[1]) | (m == s_top_i[2]);
        if ((bbi[m] != PAD_IDX) && !core) { fsum += s_items[m][t]; fcnt++; }
    }
    float hfr = fsum / fmaxf((float)fcnt, 1.f);
    s_syn[t] = hcore;
    s_syn[D + t] = hfr;
    __syncthreads();

    // --- synergy MLP (128->64->64) ---
    float h1 = sb1[t];
    for (int k = 0; k < 2 * D; ++k) h1 = fmaf(s_syn[k], sw1[k * D + t], h1);
    h1 = fmaxf(h1, 0.f);
    s_h1[t] = h1;
    __syncthreads();
    float phi = sb2[t];
    for (int k = 0; k < D; ++k) phi = fmaf(s_h1[k], sw2[k * D + t], phi);
    float hat = hcore + phi;

    // --- score = dot(u_ui, UB_b[b]) + dot(UB_u[u], hat) ---
    float ub_u = m_ub[(size_t)u * D + t];
    float ub_b = m_ub[(size_t)(NU + b) * D + t];
    float part = wave_sum64(u_ui * ub_b + ub_u * hat);
    if (t == 0) scores[n] = part;
}

// mean over batch of softplus(neg - pos)
__global__ __launch_bounds__(256) void k_loss(const float* __restrict__ scores,
                                              float* __restrict__ out) {
    __shared__ float red[256];
    float s = 0.f;
    for (int i = threadIdx.x; i < BATCH; i += 256) {
        float x = scores[i * 2 + 1] - scores[i * 2 + 0];
        s += fmaxf(x, 0.f) + log1pf(expf(-fabsf(x)));
    }
    red[threadIdx.x] = s;
    __syncthreads();
    for (int w = 128; w > 0; w >>= 1) {
        if (threadIdx.x < w) red[threadIdx.x] += red[threadIdx.x + w];
        __syncthreads();
    }
    if (threadIdx.x == 0) out[0] = red[0] / (float)BATCH;
}

extern "C" void kernel_launch(void* const* d_in, const int* in_sizes, int n_in,
                              void* d_out, int out_size, void* d_ws, size_t ws_size,
                              hipStream_t stream) {
    const float* users_feature   = (const float*)d_in[0];
    const float* bundles_feature = (const float*)d_in[1];
    const float* items_feature   = (const float*)d_in[2];
    const float* cw1 = (const float*)d_in[3];
    const float* cb1 = (const float*)d_in[4];
    const float* cw2 = (const float*)d_in[5];
    const float* cb2 = (const float*)d_in[6];
    const float* sw1 = (const float*)d_in[7];
    const float* sb1 = (const float*)d_in[8];
    const float* sw2 = (const float*)d_in[9];
    const float* sb2 = (const float*)d_in[10];
    const float* ub_val = (const float*)d_in[11];
    const float* ui_val = (const float*)d_in[12];
    const float* bi_val = (const float*)d_in[13];
    const int* users   = (const int*)d_in[14];
    const int* bundles = (const int*)d_in[15];
    const int* ub_row = (const int*)d_in[16];
    const int* ub_col = (const int*)d_in[17];
    const int* ui_row = (const int*)d_in[18];
    const int* ui_col = (const int*)d_in[19];
    const int* bi_row = (const int*)d_in[20];
    const int* bi_col = (const int*)d_in[21];
    const int* bundle_items = (const int*)d_in[22];
    const int E_UB = in_sizes[11], E_UI = in_sizes[12], E_BI = in_sizes[13];

    // workspace layout (floats)
    float* ws = (float*)d_ws;
    size_t off = 0;
    float* acc_ub = ws + off; off += (size_t)N_UB * D;
    float* acc_ui = ws + off; off += (size_t)N_UI * D;
    float* acc_bi = ws + off; off += (size_t)N_BI * D;
    float* buf0   = ws + off; off += (size_t)N_UI * D;  // max N
    float* buf1   = ws + off; off += (size_t)N_UI * D;
    float* scores = ws + off; off += (size_t)BATCH * NCAND;
    if (ws_size < off * sizeof(float)) return;  // workspace too small: fail loudly (wrong answer)

    auto propagate = [&](const int* row, const int* col, const float* val, int E,
                         const float* fa, int na, int n, const float* fb,
                         float* acc) {
        size_t tot4 = (size_t)n * D / 4;
        int blocks_init = (int)((tot4 + 255) / 256);
        float* cur = buf0;
        float* nxt = buf1;
        k_init<<<blocks_init, 256, 0, stream>>>(fa, na, n, fb, cur, acc);
        for (int layer = 0; layer < 2; ++layer) {
            hipMemsetAsync(nxt, 0, (size_t)n * D * sizeof(float), stream);
            size_t ng = (size_t)E * 16;
            k_spmm<<<(int)((ng + 255) / 256), 256, 0, stream>>>(row, col, val,
                                                                cur, nxt, E);
            k_add<<<blocks_init, 256, 0, stream>>>(acc, nxt, tot4);
            float* tmp = cur; cur = nxt; nxt = tmp;
        }
        k_scale<<<blocks_init, 256, 0, stream>>>(acc, tot4, 1.f / 3.f);
    };

    propagate(ub_row, ub_col, ub_val, E_UB, users_feature, NU, N_UB,
              bundles_feature, acc_ub);
    propagate(ui_row, ui_col, ui_val, E_UI, users_feature, NU, N_UI,
              items_feature, acc_ui);
    propagate(bi_row, bi_col, bi_val, E_BI, bundles_feature, NB, N_BI,
              items_feature, acc_bi);

    k_score<<<BATCH * NCAND, 64, 0, stream>>>(
        users, bundles, bundle_items, acc_ub, acc_ui, acc_bi,
        cw1, cb1, cw2, cb2, sw1, sb1, sw2, sb2, scores);

    k_loss<<<1, 256, 0, stream>>>(scores, (float*)d_out);
}

// Round 2
// 1288.005 us; speedup vs baseline: 4.2469x; 4.2469x over previous
//
#include <hip/hip_runtime.h>
#include <math.h>

// Problem constants (from reference)
constexpr int D = 64;
constexpr int NU = 50000, NB = 20000, NI = 100000;
constexpr int BATCH = 2048, NCAND = 2, MAXDEG = 50, CORE_K = 3;
constexpr int PAD_IDX = NI;
constexpr int N_UB = NU + NB, N_UI = NU + NI, N_BI = NB + NI;
constexpr int NMAX = N_UI;        // 150000, largest node count
constexpr int EMAX = 1200000;     // largest edge count
constexpr int SCAN_TILE = 1024;   // elems per scan block (256 thr x 4)

__device__ __forceinline__ float wave_sum64(float v) {
#pragma unroll
    for (int off = 32; off > 0; off >>= 1) v += __shfl_down(v, off);
    return v;  // valid in lane 0
}

// ---------------- CSR build ----------------

__global__ void k_hist(const int* __restrict__ row, int E, int* __restrict__ cnt) {
    int i = blockIdx.x * blockDim.x + threadIdx.x;
    if (i < E) atomicAdd(&cnt[row[i]], 1);
}

// per-block partial sums of cnt tiles (tile = 1024, thread t owns 4 contiguous)
__global__ __launch_bounds__(256) void k_scan1(const int* __restrict__ cnt, int N,
                                               int* __restrict__ bsum) {
    __shared__ int red[256];
    int base = blockIdx.x * SCAN_TILE + threadIdx.x * 4;
    int s = 0;
#pragma unroll
    for (int k = 0; k < 4; ++k) { int i = base + k; if (i < N) s += cnt[i]; }
    red[threadIdx.x] = s;
    __syncthreads();
    for (int w = 128; w > 0; w >>= 1) {
        if (threadIdx.x < w) red[threadIdx.x] += red[threadIdx.x + w];
        __syncthreads();
    }
    if (threadIdx.x == 0) bsum[blockIdx.x] = red[0];
}

// single-block exclusive scan of block sums; also writes row_start[N] = total
__global__ void k_scan2(int* __restrict__ bsum, int nb, int* __restrict__ rs_total) {
    if (threadIdx.x == 0) {
        int run = 0;
        for (int i = 0; i < nb; ++i) { int t = bsum[i]; bsum[i] = run; run += t; }
        *rs_total = run;   // == E
    }
}

// per-block exclusive scan of tile, + scanned block offset -> row_start
__global__ __launch_bounds__(256) void k_scan3(const int* __restrict__ cnt, int N,
                                               const int* __restrict__ bsum,
                                               int* __restrict__ rs) {
    __shared__ int s_ts[256];
    int t = threadIdx.x;
    int base = blockIdx.x * SCAN_TILE + t * 4;
    int v[4];
#pragma unroll
    for (int k = 0; k < 4; ++k) { int i = base + k; v[k] = (i < N) ? cnt[i] : 0; }
    int ts = v[0] + v[1] + v[2] + v[3];
    s_ts[t] = ts;
    __syncthreads();
    // Hillis-Steele inclusive scan over 256 thread sums
    for (int off = 1; off < 256; off <<= 1) {
        int add = (t >= off) ? s_ts[t - off] : 0;
        __syncthreads();
        s_ts[t] += add;
        __syncthreads();
    }
    int pre = bsum[blockIdx.x] + (s_ts[t] - ts);  // exclusive prefix for this thread
#pragma unroll
    for (int k = 0; k < 4; ++k) {
        int i = base + k;
        if (i < N) rs[i] = pre;
        pre += v[k];
    }
}

__global__ void k_copy_int(const int* __restrict__ src, int* __restrict__ dst, int n) {
    int i = blockIdx.x * blockDim.x + threadIdx.x;
    if (i < n) dst[i] = src[i];
}

__global__ void k_scatter(const int* __restrict__ row, const int* __restrict__ col,
                          const float* __restrict__ val, int E,
                          int* __restrict__ cursor,
                          int* __restrict__ col_s, float* __restrict__ val_s) {
    int i = blockIdx.x * blockDim.x + threadIdx.x;
    if (i >= E) return;
    int p = atomicAdd(&cursor[row[i]], 1);
    col_s[p] = col[i];
    val_s[p] = val[i];
}

// ---------------- propagate ----------------

// f_cur = acc = concat(feat_a, feat_b); float4-vectorized
__global__ void k_init(const float* __restrict__ fa, int na, int n,
                       const float* __restrict__ fb,
                       float* __restrict__ cur, float* __restrict__ acc) {
    size_t i = (size_t)blockIdx.x * blockDim.x + threadIdx.x;  // float4 index
    size_t total4 = (size_t)n * D / 4;
    if (i >= total4) return;
    size_t base = i * 4;
    size_t row = base >> 6;          // / D
    size_t off = base & 63;          // % D
    const float* src = (row < (size_t)na) ? (fa + row * D + off)
                                          : (fb + (row - na) * D + off);
    float4 v = *(const float4*)src;
    *(float4*)(cur + base) = v;
    *(float4*)(acc + base) = v;
}

// CSR gather SpMM, fused with acc update:
//   a = sum_j val[j] * x[col[j]]  over this row's segment
//   if (write_y) y[row] = a
//   acc[row] = (acc[row] + a) * scale
// One wave (64 lanes = feature dims) per row; 4 rows per 256-thread block.
__global__ __launch_bounds__(256) void k_spmm_csr(
    const int* __restrict__ rs, const int* __restrict__ cols,
    const float* __restrict__ vals, const float* __restrict__ x,
    float* __restrict__ y, float* __restrict__ acc,
    int N, int write_y, float scale) {
    int r = blockIdx.x * 4 + (threadIdx.x >> 6);
    int t = threadIdx.x & 63;
    if (r >= N) return;
    int s = rs[r], e = rs[r + 1];
    float a = 0.f;
    for (int j = s; j < e; ++j) {
        int c = cols[j];        // wave-uniform
        float v = vals[j];      // wave-uniform
        a = fmaf(v, x[(size_t)c * D + t], a);
    }
    size_t o = (size_t)r * D + t;
    if (write_y) y[o] = a;
    acc[o] = (acc[o] + a) * scale;
}

// ---------------- scoring ----------------

// One wave (64 threads) per candidate pair n in [0, BATCH*NCAND).
// m_ub: [N_UB,D] = [UB_u ; UB_b], m_ui: [N_UI,D] = [UI_u ; UI_i],
// m_bi: [N_BI,D] = [BI_b ; BI_i]   (already scaled by 1/3 = mean over hops)
__global__ __launch_bounds__(64) void k_score(
    const int* __restrict__ users, const int* __restrict__ bundles,
    const int* __restrict__ bundle_items,
    const float* __restrict__ m_ub, const float* __restrict__ m_ui,
    const float* __restrict__ m_bi,
    const float* __restrict__ cw1, const float* __restrict__ cb1,
    const float* __restrict__ cw2, const float* __restrict__ cb2,
    const float* __restrict__ sw1, const float* __restrict__ sb1,
    const float* __restrict__ sw2, const float* __restrict__ sb2,
    float* __restrict__ scores) {
    const int n = blockIdx.x;
    const int t = threadIdx.x;  // 0..63 == feature dim
    const int u = users[n / NCAND];
    const int b = bundles[n];
    const int* bbi = bundle_items + (size_t)b * MAXDEG;

    __shared__ float s_items[MAXDEG][D];   // items_ui stash (12.8 KB)
    __shared__ float s_r[2][MAXDEG];       // r_UI, r_BI
    __shared__ float s_pi[MAXDEG];
    __shared__ int   s_top_i[CORE_K];
    __shared__ float s_top_p[CORE_K];
    __shared__ float s_syn[2 * D];
    __shared__ float s_h1[D];

    const float u_ui = m_ui[(size_t)u * D + t];          // UI_u[u]
    const float b_bi = m_bi[(size_t)b * D + t];          // BI_b[b]

    // --- 50 dot products against UI_i / BI_i item rows ---
    for (int m = 0; m < MAXDEG; ++m) {
        int it = bbi[m];
        float iu = 0.f, ib = 0.f;
        if (it != PAD_IDX) {
            iu = m_ui[(size_t)(NU + it) * D + t];
            ib = m_bi[(size_t)(NB + it) * D + t];
        }
        s_items[m][t] = iu;
        float pu = wave_sum64(u_ui * iu);
        float pb = wave_sum64(b_bi * ib);
        if (t == 0) { s_r[0][m] = pu; s_r[1][m] = pb; }
    }
    __syncthreads();

    // --- core MLP (2->32->1) per item, lanes 0..49 ---
    float logit = -INFINITY;
    if (t < MAXDEG) {
        float rU = s_r[0][t], rB = s_r[1][t];
        float acc = cb2[0];
#pragma unroll
        for (int j = 0; j < 32; ++j) {
            float h = fmaf(rU, cw1[j], fmaf(rB, cw1[32 + j], cb1[j]));
            h = fmaxf(h, 0.f);
            acc = fmaf(h, cw2[j], acc);
        }
        logit = (bbi[t] != PAD_IDX) ? acc : -INFINITY;
    }

    // --- softmax over 50 (lanes >= 50 contribute -inf / 0) ---
    float mx = logit;
#pragma unroll
    for (int off = 32; off > 0; off >>= 1) mx = fmaxf(mx, __shfl_down(mx, off));
    mx = __shfl(mx, 0);
    float ex = (t < MAXDEG) ? expf(logit - mx) : 0.f;
    float sm = wave_sum64(ex);
    sm = __shfl(sm, 0);
    if (t < MAXDEG) s_pi[t] = ex / sm;
    __syncthreads();

    // --- top-3 (serial on lane 0; strict > keeps lowest index on ties,
    //     matching jax.lax.top_k) ---
    if (t == 0) {
        bool used[MAXDEG];
        for (int m = 0; m < MAXDEG; ++m) used[m] = false;
        float tsum = 0.f;
        for (int k = 0; k < CORE_K; ++k) {
            float best = -1.f; int bidx = 0;
            for (int m = 0; m < MAXDEG; ++m)
                if (!used[m] && s_pi[m] > best) { best = s_pi[m]; bidx = m; }
            used[bidx] = true;
            s_top_i[k] = bidx;
            s_top_p[k] = best;
            tsum += best;
        }
        float inv = 1.f / (tsum + 1e-10f);
        for (int k = 0; k < CORE_K; ++k) s_top_p[k] *= inv;
    }
    __syncthreads();

    // --- h_core / h_fringe (per-lane feature dim t) ---
    float hcore = 0.f;
#pragma unroll
    for (int k = 0; k < CORE_K; ++k)
        hcore = fmaf(s_items[s_top_i[k]][t], s_top_p[k], hcore);

    float fsum = 0.f; int fcnt = 0;
    for (int m = 0; m < MAXDEG; ++m) {
        bool core = (m == s_top_i[0]) | (m == s_top_i[1]) | (m == s_top_i[2]);
        if ((bbi[m] != PAD_IDX) && !core) { fsum += s_items[m][t]; fcnt++; }
    }
    float hfr = fsum / fmaxf((float)fcnt, 1.f);
    s_syn[t] = hcore;
    s_syn[D + t] = hfr;
    __syncthreads();

    // --- synergy MLP (128->64->64) ---
    float h1 = sb1[t];
    for (int k = 0; k < 2 * D; ++k) h1 = fmaf(s_syn[k], sw1[k * D + t], h1);
    h1 = fmaxf(h1, 0.f);
    s_h1[t] = h1;
    __syncthreads();
    float phi = sb2[t];
    for (int k = 0; k < D; ++k) phi = fmaf(s_h1[k], sw2[k * D + t], phi);
    float hat = hcore + phi;

    // --- score = dot(u_ui, UB_b[b]) + dot(UB_u[u], hat) ---
    float ub_u = m_ub[(size_t)u * D + t];
    float ub_b = m_ub[(size_t)(NU + b) * D + t];
    float part = wave_sum64(u_ui * ub_b + ub_u * hat);
    if (t == 0) scores[n] = part;
}

// mean over batch of softplus(neg - pos)
__global__ __launch_bounds__(256) void k_loss(const float* __restrict__ scores,
                                              float* __restrict__ out) {
    __shared__ float red[256];
    float s = 0.f;
    for (int i = threadIdx.x; i < BATCH; i += 256) {
        float x = scores[i * 2 + 1] - scores[i * 2 + 0];
        s += fmaxf(x, 0.f) + log1pf(expf(-fabsf(x)));
    }
    red[threadIdx.x] = s;
    __syncthreads();
    for (int w = 128; w > 0; w >>= 1) {
        if (threadIdx.x < w) red[threadIdx.x] += red[threadIdx.x + w];
        __syncthreads();
    }
    if (threadIdx.x == 0) out[0] = red[0] / (float)BATCH;
}

extern "C" void kernel_launch(void* const* d_in, const int* in_sizes, int n_in,
                              void* d_out, int out_size, void* d_ws, size_t ws_size,
                              hipStream_t stream) {
    const float* users_feature   = (const float*)d_in[0];
    const float* bundles_feature = (const float*)d_in[1];
    const float* items_feature   = (const float*)d_in[2];
    const float* cw1 = (const float*)d_in[3];
    const float* cb1 = (const float*)d_in[4];
    const float* cw2 = (const float*)d_in[5];
    const float* cb2 = (const float*)d_in[6];
    const float* sw1 = (const float*)d_in[7];
    const float* sb1 = (const float*)d_in[8];
    const float* sw2 = (const float*)d_in[9];
    const float* sb2 = (const float*)d_in[10];
    const float* ub_val = (const float*)d_in[11];
    const float* ui_val = (const float*)d_in[12];
    const float* bi_val = (const float*)d_in[13];
    const int* users   = (const int*)d_in[14];
    const int* bundles = (const int*)d_in[15];
    const int* ub_row = (const int*)d_in[16];
    const int* ub_col = (const int*)d_in[17];
    const int* ui_row = (const int*)d_in[18];
    const int* ui_col = (const int*)d_in[19];
    const int* bi_row = (const int*)d_in[20];
    const int* bi_col = (const int*)d_in[21];
    const int* bundle_items = (const int*)d_in[22];
    const int E_UB = in_sizes[11], E_UI = in_sizes[12], E_BI = in_sizes[13];

    // workspace layout (4-byte elements)
    float* ws = (float*)d_ws;
    size_t off = 0;
    float* acc_ub = ws + off; off += (size_t)N_UB * D;
    float* acc_ui = ws + off; off += (size_t)N_UI * D;
    float* acc_bi = ws + off; off += (size_t)N_BI * D;
    float* buf0   = ws + off; off += (size_t)N_UI * D;  // max N
    float* buf1   = ws + off; off += (size_t)N_UI * D;
    float* scores = ws + off; off += (size_t)BATCH * NCAND;
    int*   cnt    = (int*)(ws + off); off += NMAX;
    int*   rstart = (int*)(ws + off); off += NMAX + 1;
    int*   cursor = (int*)(ws + off); off += NMAX;
    int*   bsum   = (int*)(ws + off); off += 256;       // scan block sums (<=147)
    int*   col_s  = (int*)(ws + off); off += EMAX;
    float* val_s  = ws + off; off += EMAX;
    if (ws_size < off * sizeof(float)) return;  // workspace too small: fail loudly

    auto propagate = [&](const int* row, const int* col, const float* val, int E,
                         const float* fa, int na, int n, const float* fb,
                         float* acc) {
        // ---- CSR build ----
        hipMemsetAsync(cnt, 0, (size_t)n * sizeof(int), stream);
        k_hist<<<(E + 255) / 256, 256, 0, stream>>>(row, E, cnt);
        int nb = (n + SCAN_TILE - 1) / SCAN_TILE;
        k_scan1<<<nb, 256, 0, stream>>>(cnt, n, bsum);
        k_scan2<<<1, 64, 0, stream>>>(bsum, nb, rstart + n);
        k_scan3<<<nb, 256, 0, stream>>>(cnt, n, bsum, rstart);
        k_copy_int<<<(n + 255) / 256, 256, 0, stream>>>(rstart, cursor, n);
        k_scatter<<<(E + 255) / 256, 256, 0, stream>>>(row, col, val, E,
                                                       cursor, col_s, val_s);
        // ---- init + 2 gather-SpMM layers (acc-update fused) ----
        size_t tot4 = (size_t)n * D / 4;
        int blocks_init = (int)((tot4 + 255) / 256);
        k_init<<<blocks_init, 256, 0, stream>>>(fa, na, n, fb, buf0, acc);
        int sb = (n + 3) / 4;
        k_spmm_csr<<<sb, 256, 0, stream>>>(rstart, col_s, val_s, buf0, buf1,
                                           acc, n, 1, 1.0f);
        k_spmm_csr<<<sb, 256, 0, stream>>>(rstart, col_s, val_s, buf1, buf0,
                                           acc, n, 0, 1.0f / 3.0f);
    };

    propagate(ub_row, ub_col, ub_val, E_UB, users_feature, NU, N_UB,
              bundles_feature, acc_ub);
    propagate(ui_row, ui_col, ui_val, E_UI, users_feature, NU, N_UI,
              items_feature, acc_ui);
    propagate(bi_row, bi_col, bi_val, E_BI, bundles_feature, NB, N_BI,
              items_feature, acc_bi);

    k_score<<<BATCH * NCAND, 64, 0, stream>>>(
        users, bundles, bundle_items, acc_ub, acc_ui, acc_bi,
        cw1, cb1, cw2, cb2, sw1, sb1, sw2, sb2, scores);

    k_loss<<<1, 256, 0, stream>>>(scores, (float*)d_out);
}

// Round 3
// 882.714 us; speedup vs baseline: 6.1968x; 1.4591x over previous
//
#include <hip/hip_runtime.h>
#include <math.h>

// Problem constants (from reference)
constexpr int D = 64;
constexpr int NU = 50000, NB = 20000, NI = 100000;
constexpr int BATCH = 2048, NCAND = 2, MAXDEG = 50, CORE_K = 3;
constexpr int PAD_IDX = NI;
constexpr int N_UB = NU + NB, N_UI = NU + NI, N_BI = NB + NI;
constexpr int NMAX = N_UI;        // 150000, largest node count
constexpr int EMAX = 1200000;     // largest edge count
constexpr int SCAN_TILE = 1024;   // elems per scan block (256 thr x 4)

__device__ __forceinline__ float wave_sum64(float v) {
#pragma unroll
    for (int off = 32; off > 0; off >>= 1) v += __shfl_down(v, off);
    return v;  // valid in lane 0
}

// ---------------- CSR build ----------------

__global__ void k_hist(const int* __restrict__ row, int E, int* __restrict__ cnt) {
    int i = blockIdx.x * blockDim.x + threadIdx.x;
    if (i < E) atomicAdd(&cnt[row[i]], 1);
}

// per-block partial sums of cnt tiles (tile = 1024, thread t owns 4 contiguous)
__global__ __launch_bounds__(256) void k_scan1(const int* __restrict__ cnt, int N,
                                               int* __restrict__ bsum) {
    __shared__ int red[256];
    int base = blockIdx.x * SCAN_TILE + threadIdx.x * 4;
    int s = 0;
#pragma unroll
    for (int k = 0; k < 4; ++k) { int i = base + k; if (i < N) s += cnt[i]; }
    red[threadIdx.x] = s;
    __syncthreads();
    for (int w = 128; w > 0; w >>= 1) {
        if (threadIdx.x < w) red[threadIdx.x] += red[threadIdx.x + w];
        __syncthreads();
    }
    if (threadIdx.x == 0) bsum[blockIdx.x] = red[0];
}

// single-block exclusive scan of block sums; also writes row_start[N] = total
__global__ void k_scan2(int* __restrict__ bsum, int nb, int* __restrict__ rs_total) {
    if (threadIdx.x == 0) {
        int run = 0;
        for (int i = 0; i < nb; ++i) { int t = bsum[i]; bsum[i] = run; run += t; }
        *rs_total = run;   // == E
    }
}

// per-block exclusive scan of tile, + scanned block offset -> row_start & cursor
__global__ __launch_bounds__(256) void k_scan3(const int* __restrict__ cnt, int N,
                                               const int* __restrict__ bsum,
                                               int* __restrict__ rs,
                                               int* __restrict__ cursor) {
    __shared__ int s_ts[256];
    int t = threadIdx.x;
    int base = blockIdx.x * SCAN_TILE + t * 4;
    int v[4];
#pragma unroll
    for (int k = 0; k < 4; ++k) { int i = base + k; v[k] = (i < N) ? cnt[i] : 0; }
    int ts = v[0] + v[1] + v[2] + v[3];
    s_ts[t] = ts;
    __syncthreads();
    // Hillis-Steele inclusive scan over 256 thread sums
    for (int off = 1; off < 256; off <<= 1) {
        int add = (t >= off) ? s_ts[t - off] : 0;
        __syncthreads();
        s_ts[t] += add;
        __syncthreads();
    }
    int pre = bsum[blockIdx.x] + (s_ts[t] - ts);  // exclusive prefix for this thread
#pragma unroll
    for (int k = 0; k < 4; ++k) {
        int i = base + k;
        if (i < N) { rs[i] = pre; cursor[i] = pre; }
        pre += v[k];
    }
}

__global__ void k_scatter(const int* __restrict__ row, const int* __restrict__ col,
                          const float* __restrict__ val, int E,
                          int* __restrict__ cursor,
                          int* __restrict__ col_s, float* __restrict__ val_s) {
    int i = blockIdx.x * blockDim.x + threadIdx.x;
    if (i >= E) return;
    int p = atomicAdd(&cursor[row[i]], 1);
    col_s[p] = col[i];
    val_s[p] = val[i];
}

// ---------------- propagate (CSR gather, 16 lanes x float4 per row) --------

// layer 1: y1[r] = sum_j val[j] * f[col[j]]  where f = concat(fa, fb)
__global__ __launch_bounds__(256) void k_spmm_l1(
    const int* __restrict__ rs, const int* __restrict__ cols,
    const float* __restrict__ vals,
    const float* __restrict__ fa, const float* __restrict__ fb, int na,
    float* __restrict__ y1, int N) {
    int r = blockIdx.x * 16 + (threadIdx.x >> 4);
    int t = threadIdx.x & 15;            // float4 lane within row
    if (r >= N) return;
    int s = rs[r], e = rs[r + 1];
    float4 a0 = {0.f, 0.f, 0.f, 0.f}, a1 = {0.f, 0.f, 0.f, 0.f};
    int j = s;
    for (; j + 1 < e; j += 2) {
        int c0 = cols[j], c1 = cols[j + 1];
        float v0 = vals[j], v1 = vals[j + 1];
        const float* p0 = (c0 < na) ? fa + (size_t)c0 * D : fb + (size_t)(c0 - na) * D;
        const float* p1 = (c1 < na) ? fa + (size_t)c1 * D : fb + (size_t)(c1 - na) * D;
        float4 x0 = *(const float4*)(p0 + t * 4);
        float4 x1 = *(const float4*)(p1 + t * 4);
        a0.x = fmaf(v0, x0.x, a0.x); a0.y = fmaf(v0, x0.y, a0.y);
        a0.z = fmaf(v0, x0.z, a0.z); a0.w = fmaf(v0, x0.w, a0.w);
        a1.x = fmaf(v1, x1.x, a1.x); a1.y = fmaf(v1, x1.y, a1.y);
        a1.z = fmaf(v1, x1.z, a1.z); a1.w = fmaf(v1, x1.w, a1.w);
    }
    if (j < e) {
        int c0 = cols[j];
        float v0 = vals[j];
        const float* p0 = (c0 < na) ? fa + (size_t)c0 * D : fb + (size_t)(c0 - na) * D;
        float4 x0 = *(const float4*)(p0 + t * 4);
        a0.x = fmaf(v0, x0.x, a0.x); a0.y = fmaf(v0, x0.y, a0.y);
        a0.z = fmaf(v0, x0.z, a0.z); a0.w = fmaf(v0, x0.w, a0.w);
    }
    a0.x += a1.x; a0.y += a1.y; a0.z += a1.z; a0.w += a1.w;
    *(float4*)(y1 + (size_t)r * D + t * 4) = a0;
}

// layer 2 fused with mean: acc[r] = (f[r] + y1[r] + sum_j val[j]*y1[col[j]]) / 3
__global__ __launch_bounds__(256) void k_spmm_l2(
    const int* __restrict__ rs, const int* __restrict__ cols,
    const float* __restrict__ vals, const float* __restrict__ y1,
    const float* __restrict__ fa, const float* __restrict__ fb, int na,
    float* __restrict__ acc, int N) {
    int r = blockIdx.x * 16 + (threadIdx.x >> 4);
    int t = threadIdx.x & 15;
    if (r >= N) return;
    int s = rs[r], e = rs[r + 1];
    float4 a0 = {0.f, 0.f, 0.f, 0.f}, a1 = {0.f, 0.f, 0.f, 0.f};
    int j = s;
    for (; j + 1 < e; j += 2) {
        int c0 = cols[j], c1 = cols[j + 1];
        float v0 = vals[j], v1 = vals[j + 1];
        float4 x0 = *(const float4*)(y1 + (size_t)c0 * D + t * 4);
        float4 x1 = *(const float4*)(y1 + (size_t)c1 * D + t * 4);
        a0.x = fmaf(v0, x0.x, a0.x); a0.y = fmaf(v0, x0.y, a0.y);
        a0.z = fmaf(v0, x0.z, a0.z); a0.w = fmaf(v0, x0.w, a0.w);
        a1.x = fmaf(v1, x1.x, a1.x); a1.y = fmaf(v1, x1.y, a1.y);
        a1.z = fmaf(v1, x1.z, a1.z); a1.w = fmaf(v1, x1.w, a1.w);
    }
    if (j < e) {
        int c0 = cols[j];
        float v0 = vals[j];
        float4 x0 = *(const float4*)(y1 + (size_t)c0 * D + t * 4);
        a0.x = fmaf(v0, x0.x, a0.x); a0.y = fmaf(v0, x0.y, a0.y);
        a0.z = fmaf(v0, x0.z, a0.z); a0.w = fmaf(v0, x0.w, a0.w);
    }
    const float* pf = (r < na) ? fa + (size_t)r * D : fb + (size_t)(r - na) * D;
    float4 f0 = *(const float4*)(pf + t * 4);
    float4 yv = *(const float4*)(y1 + (size_t)r * D + t * 4);
    constexpr float k3 = 1.0f / 3.0f;
    float4 o;
    o.x = (f0.x + yv.x + a0.x + a1.x) * k3;
    o.y = (f0.y + yv.y + a0.y + a1.y) * k3;
    o.z = (f0.z + yv.z + a0.z + a1.z) * k3;
    o.w = (f0.w + yv.w + a0.w + a1.w) * k3;
    *(float4*)(acc + (size_t)r * D + t * 4) = o;
}

// ---------------- scoring ----------------

// One wave (64 threads) per candidate pair n in [0, BATCH*NCAND).
// m_ub: [N_UB,D] = [UB_u ; UB_b], m_ui: [N_UI,D] = [UI_u ; UI_i],
// m_bi: [N_BI,D] = [BI_b ; BI_i]   (already scaled by 1/3 = mean over hops)
__global__ __launch_bounds__(64) void k_score(
    const int* __restrict__ users, const int* __restrict__ bundles,
    const int* __restrict__ bundle_items,
    const float* __restrict__ m_ub, const float* __restrict__ m_ui,
    const float* __restrict__ m_bi,
    const float* __restrict__ cw1, const float* __restrict__ cb1,
    const float* __restrict__ cw2, const float* __restrict__ cb2,
    const float* __restrict__ sw1, const float* __restrict__ sb1,
    const float* __restrict__ sw2, const float* __restrict__ sb2,
    float* __restrict__ scores) {
    const int n = blockIdx.x;
    const int t = threadIdx.x;  // 0..63 == feature dim
    const int u = users[n / NCAND];
    const int b = bundles[n];
    const int* bbi = bundle_items + (size_t)b * MAXDEG;

    __shared__ float s_items[MAXDEG][D];   // items_ui stash (12.8 KB)
    __shared__ float s_r[2][MAXDEG];       // r_UI, r_BI
    __shared__ float s_pi[MAXDEG];
    __shared__ int   s_top_i[CORE_K];
    __shared__ float s_top_p[CORE_K];
    __shared__ float s_syn[2 * D];
    __shared__ float s_h1[D];

    const float u_ui = m_ui[(size_t)u * D + t];          // UI_u[u]
    const float b_bi = m_bi[(size_t)b * D + t];          // BI_b[b]

    // --- 50 dot products against UI_i / BI_i item rows ---
    for (int m = 0; m < MAXDEG; ++m) {
        int it = bbi[m];
        float iu = 0.f, ib = 0.f;
        if (it != PAD_IDX) {
            iu = m_ui[(size_t)(NU + it) * D + t];
            ib = m_bi[(size_t)(NB + it) * D + t];
        }
        s_items[m][t] = iu;
        float pu = wave_sum64(u_ui * iu);
        float pb = wave_sum64(b_bi * ib);
        if (t == 0) { s_r[0][m] = pu; s_r[1][m] = pb; }
    }
    __syncthreads();

    // --- core MLP (2->32->1) per item, lanes 0..49 ---
    float logit = -INFINITY;
    if (t < MAXDEG) {
        float rU = s_r[0][t], rB = s_r[1][t];
        float acc = cb2[0];
#pragma unroll
        for (int j = 0; j < 32; ++j) {
            float h = fmaf(rU, cw1[j], fmaf(rB, cw1[32 + j], cb1[j]));
            h = fmaxf(h, 0.f);
            acc = fmaf(h, cw2[j], acc);
        }
        logit = (bbi[t] != PAD_IDX) ? acc : -INFINITY;
    }

    // --- softmax over 50 (lanes >= 50 contribute -inf / 0) ---
    float mx = logit;
#pragma unroll
    for (int off = 32; off > 0; off >>= 1) mx = fmaxf(mx, __shfl_down(mx, off));
    mx = __shfl(mx, 0);
    float ex = (t < MAXDEG) ? expf(logit - mx) : 0.f;
    float sm = wave_sum64(ex);
    sm = __shfl(sm, 0);
    if (t < MAXDEG) s_pi[t] = ex / sm;
    __syncthreads();

    // --- top-3 (serial on lane 0; strict > keeps lowest index on ties,
    //     matching jax.lax.top_k) ---
    if (t == 0) {
        bool used[MAXDEG];
        for (int m = 0; m < MAXDEG; ++m) used[m] = false;
        float tsum = 0.f;
        for (int k = 0; k < CORE_K; ++k) {
            float best = -1.f; int bidx = 0;
            for (int m = 0; m < MAXDEG; ++m)
                if (!used[m] && s_pi[m] > best) { best = s_pi[m]; bidx = m; }
            used[bidx] = true;
            s_top_i[k] = bidx;
            s_top_p[k] = best;
            tsum += best;
        }
        float inv = 1.f / (tsum + 1e-10f);
        for (int k = 0; k < CORE_K; ++k) s_top_p[k] *= inv;
    }
    __syncthreads();

    // --- h_core / h_fringe (per-lane feature dim t) ---
    float hcore = 0.f;
#pragma unroll
    for (int k = 0; k < CORE_K; ++k)
        hcore = fmaf(s_items[s_top_i[k]][t], s_top_p[k], hcore);

    float fsum = 0.f; int fcnt = 0;
    for (int m = 0; m < MAXDEG; ++m) {
        bool core = (m == s_top_i[0]) | (m == s_top_i[1]) | (m == s_top_i[2]);
        if ((bbi[m] != PAD_IDX) && !core) { fsum += s_items[m][t]; fcnt++; }
    }
    float hfr = fsum / fmaxf((float)fcnt, 1.f);
    s_syn[t] = hcore;
    s_syn[D + t] = hfr;
    __syncthreads();

    // --- synergy MLP (128->64->64) ---
    float h1 = sb1[t];
    for (int k = 0; k < 2 * D; ++k) h1 = fmaf(s_syn[k], sw1[k * D + t], h1);
    h1 = fmaxf(h1, 0.f);
    s_h1[t] = h1;
    __syncthreads();
    float phi = sb2[t];
    for (int k = 0; k < D; ++k) phi = fmaf(s_h1[k], sw2[k * D + t], phi);
    float hat = hcore + phi;

    // --- score = dot(u_ui, UB_b[b]) + dot(UB_u[u], hat) ---
    float ub_u = m_ub[(size_t)u * D + t];
    float ub_b = m_ub[(size_t)(NU + b) * D + t];
    float part = wave_sum64(u_ui * ub_b + ub_u * hat);
    if (t == 0) scores[n] = part;
}

// mean over batch of softplus(neg - pos)
__global__ __launch_bounds__(256) void k_loss(const float* __restrict__ scores,
                                              float* __restrict__ out) {
    __shared__ float red[256];
    float s = 0.f;
    for (int i = threadIdx.x; i < BATCH; i += 256) {
        float x = scores[i * 2 + 1] - scores[i * 2 + 0];
        s += fmaxf(x, 0.f) + log1pf(expf(-fabsf(x)));
    }
    red[threadIdx.x] = s;
    __syncthreads();
    for (int w = 128; w > 0; w >>= 1) {
        if (threadIdx.x < w) red[threadIdx.x] += red[threadIdx.x + w];
        __syncthreads();
    }
    if (threadIdx.x == 0) out[0] = red[0] / (float)BATCH;
}

extern "C" void kernel_launch(void* const* d_in, const int* in_sizes, int n_in,
                              void* d_out, int out_size, void* d_ws, size_t ws_size,
                              hipStream_t stream) {
    const float* users_feature   = (const float*)d_in[0];
    const float* bundles_feature = (const float*)d_in[1];
    const float* items_feature   = (const float*)d_in[2];
    const float* cw1 = (const float*)d_in[3];
    const float* cb1 = (const float*)d_in[4];
    const float* cw2 = (const float*)d_in[5];
    const float* cb2 = (const float*)d_in[6];
    const float* sw1 = (const float*)d_in[7];
    const float* sb1 = (const float*)d_in[8];
    const float* sw2 = (const float*)d_in[9];
    const float* sb2 = (const float*)d_in[10];
    const float* ub_val = (const float*)d_in[11];
    const float* ui_val = (const float*)d_in[12];
    const float* bi_val = (const float*)d_in[13];
    const int* users   = (const int*)d_in[14];
    const int* bundles = (const int*)d_in[15];
    const int* ub_row = (const int*)d_in[16];
    const int* ub_col = (const int*)d_in[17];
    const int* ui_row = (const int*)d_in[18];
    const int* ui_col = (const int*)d_in[19];
    const int* bi_row = (const int*)d_in[20];
    const int* bi_col = (const int*)d_in[21];
    const int* bundle_items = (const int*)d_in[22];
    const int E_UB = in_sizes[11], E_UI = in_sizes[12], E_BI = in_sizes[13];

    // workspace layout (4-byte elements)
    float* ws = (float*)d_ws;
    size_t off = 0;
    float* acc_ub = ws + off; off += (size_t)N_UB * D;
    float* acc_ui = ws + off; off += (size_t)N_UI * D;
    float* acc_bi = ws + off; off += (size_t)N_BI * D;
    float* y1buf  = ws + off; off += (size_t)N_UI * D;  // max N
    float* scores = ws + off; off += (size_t)BATCH * NCAND;
    int*   cnt    = (int*)(ws + off); off += NMAX;
    int*   rstart = (int*)(ws + off); off += NMAX + 1;
    int*   cursor = (int*)(ws + off); off += NMAX;
    int*   bsum   = (int*)(ws + off); off += 256;       // scan block sums (<=147)
    int*   col_s  = (int*)(ws + off); off += EMAX;
    float* val_s  = ws + off; off += EMAX;
    if (ws_size < off * sizeof(float)) return;  // workspace too small: fail loudly

    auto propagate = [&](const int* row, const int* col, const float* val, int E,
                         const float* fa, int na, int n, const float* fb,
                         float* acc) {
        // ---- CSR build ----
        hipMemsetAsync(cnt, 0, (size_t)n * sizeof(int), stream);
        k_hist<<<(E + 255) / 256, 256, 0, stream>>>(row, E, cnt);
        int nb = (n + SCAN_TILE - 1) / SCAN_TILE;
        k_scan1<<<nb, 256, 0, stream>>>(cnt, n, bsum);
        k_scan2<<<1, 64, 0, stream>>>(bsum, nb, rstart + n);
        k_scan3<<<nb, 256, 0, stream>>>(cnt, n, bsum, rstart, cursor);
        k_scatter<<<(E + 255) / 256, 256, 0, stream>>>(row, col, val, E,
                                                       cursor, col_s, val_s);
        // ---- 2 gather-SpMM layers (init + acc fused) ----
        int sb = (n + 15) / 16;
        k_spmm_l1<<<sb, 256, 0, stream>>>(rstart, col_s, val_s, fa, fb, na,
                                          y1buf, n);
        k_spmm_l2<<<sb, 256, 0, stream>>>(rstart, col_s, val_s, y1buf, fa, fb,
                                          na, acc, n);
    };

    propagate(ub_row, ub_col, ub_val, E_UB, users_feature, NU, N_UB,
              bundles_feature, acc_ub);
    propagate(ui_row, ui_col, ui_val, E_UI, users_feature, NU, N_UI,
              items_feature, acc_ui);
    propagate(bi_row, bi_col, bi_val, E_BI, bundles_feature, NB, N_BI,
              items_feature, acc_bi);

    k_score<<<BATCH * NCAND, 64, 0, stream>>>(
        users, bundles, bundle_items, acc_ub, acc_ui, acc_bi,
        cw1, cb1, cw2, cb2, sw1, sb1, sw2, sb2, scores);

    k_loss<<<1, 256, 0, stream>>>(scores, (float*)d_out);
}

// Round 6
// 835.973 us; speedup vs baseline: 6.5433x; 1.0559x over previous
//
#include <hip/hip_runtime.h>
#include <math.h>

// Problem constants (from reference)
constexpr int D = 64;
constexpr int NU = 50000, NB = 20000, NI = 100000;
constexpr int BATCH = 2048, NCAND = 2, MAXDEG = 50, CORE_K = 3;
constexpr int PAD_IDX = NI;
constexpr int N_UB = NU + NB, N_UI = NU + NI, N_BI = NB + NI;
constexpr int N_TOT = N_UB + N_UI + N_BI;   // 340000 combined node space
constexpr int OFF1 = N_UB;                  // UI node base
constexpr int OFF2 = N_UB + N_UI;           // BI node base
constexpr int SCAN_TILE = 1024;             // elems per scan block (256 thr x 4)

__device__ __forceinline__ float wave_sum64(float v) {
#pragma unroll
    for (int off = 32; off > 0; off >>= 1) v += __shfl_down(v, off);
    return v;  // valid in lane 0
}

// NOTE: function, not macro — a macro param named `x` would capture the `.x`
// member token in the body (R4 compile failure).
__device__ __forceinline__ void fma4(float4& a, float v, const float4& u) {
    a.x = fmaf(v, u.x, a.x); a.y = fmaf(v, u.y, a.y);
    a.z = fmaf(v, u.z, a.z); a.w = fmaf(v, u.w, a.w);
}

// ---------------- fused CSR build over combined node space ----------------

__global__ void k_hist3(const int* __restrict__ r0, const int* __restrict__ r1,
                        const int* __restrict__ r2, int e0, int e1, int e2,
                        int* __restrict__ cnt) {
    int i = blockIdx.x * blockDim.x + threadIdx.x;
    if (i >= e0 + e1 + e2) return;
    int r;
    if (i < e0) r = r0[i];
    else if (i < e0 + e1) r = r1[i - e0] + OFF1;
    else r = r2[i - e0 - e1] + OFF2;
    atomicAdd(&cnt[r], 1);
}

// per-block partial sums of cnt tiles (tile = 1024, thread t owns 4 contiguous)
__global__ __launch_bounds__(256) void k_scan1(const int* __restrict__ cnt, int N,
                                               int* __restrict__ bsum) {
    __shared__ int red[256];
    int base = blockIdx.x * SCAN_TILE + threadIdx.x * 4;
    int s = 0;
#pragma unroll
    for (int k = 0; k < 4; ++k) { int i = base + k; if (i < N) s += cnt[i]; }
    red[threadIdx.x] = s;
    __syncthreads();
    for (int w = 128; w > 0; w >>= 1) {
        if (threadIdx.x < w) red[threadIdx.x] += red[threadIdx.x + w];
        __syncthreads();
    }
    if (threadIdx.x == 0) bsum[blockIdx.x] = red[0];
}

// single-thread exclusive scan of block sums (R3-proven serial version);
// also writes rs[N] = total
__global__ void k_scan2(int* __restrict__ bsum, int nb, int* __restrict__ rs_total) {
    if (threadIdx.x == 0) {
        int run = 0;
        for (int i = 0; i < nb; ++i) { int t = bsum[i]; bsum[i] = run; run += t; }
        *rs_total = run;   // == E_tot
    }
}

// per-block exclusive scan of tile, + scanned block offset -> row_start & cursor
__global__ __launch_bounds__(256) void k_scan3(const int* __restrict__ cnt, int N,
                                               const int* __restrict__ bsum,
                                               int* __restrict__ rs,
                                               int* __restrict__ cursor) {
    __shared__ int s_ts[256];
    int t = threadIdx.x;
    int base = blockIdx.x * SCAN_TILE + t * 4;
    int v[4];
#pragma unroll
    for (int k = 0; k < 4; ++k) { int i = base + k; v[k] = (i < N) ? cnt[i] : 0; }
    int ts = v[0] + v[1] + v[2] + v[3];
    s_ts[t] = ts;
    __syncthreads();
    for (int off = 1; off < 256; off <<= 1) {
        int add = (t >= off) ? s_ts[t - off] : 0;
        __syncthreads();
        s_ts[t] += add;
        __syncthreads();
    }
    int pre = bsum[blockIdx.x] + (s_ts[t] - ts);
#pragma unroll
    for (int k = 0; k < 4; ++k) {
        int i = base + k;
        if (i < N) { rs[i] = pre; cursor[i] = pre; }
        pre += v[k];
    }
}

// scatter all three edge lists; cols stored GRAPH-LOCAL
__global__ void k_scatter3(const int* __restrict__ r0, const int* __restrict__ c0,
                           const float* __restrict__ v0,
                           const int* __restrict__ r1, const int* __restrict__ c1,
                           const float* __restrict__ v1,
                           const int* __restrict__ r2, const int* __restrict__ c2,
                           const float* __restrict__ v2,
                           int e0, int e1, int e2,
                           int* __restrict__ cursor,
                           int* __restrict__ col_s, float* __restrict__ val_s) {
    int i = blockIdx.x * blockDim.x + threadIdx.x;
    if (i >= e0 + e1 + e2) return;
    int r, c; float v;
    if (i < e0)            { r = r0[i];          c = c0[i];          v = v0[i]; }
    else if (i < e0 + e1)  { int k = i - e0;      r = r1[k] + OFF1;   c = c1[k]; v = v1[k]; }
    else                   { int k = i - e0 - e1; r = r2[k] + OFF2;   c = c2[k]; v = v2[k]; }
    int p = atomicAdd(&cursor[r], 1);
    col_s[p] = c;
    val_s[p] = v;
}

// ---------------- propagate (CSR gather, 16 lanes x float4 per row) --------

// layer 1: y1[r] = sum_j val[j] * f[col[j]]  where f = concat(fa, fb), cols local
__global__ __launch_bounds__(256) void k_spmm_l1(
    const int* __restrict__ rs, const int* __restrict__ cols,
    const float* __restrict__ vals,
    const float* __restrict__ fa, const float* __restrict__ fb, int na,
    float* __restrict__ y1, int N) {
    int r = blockIdx.x * 16 + (threadIdx.x >> 4);
    int t = threadIdx.x & 15;
    if (r >= N) return;
    int s = rs[r], e = rs[r + 1];
    float4 a0 = {0,0,0,0}, a1 = {0,0,0,0}, a2 = {0,0,0,0}, a3 = {0,0,0,0};
    int j = s;
    for (; j + 3 < e; j += 4) {
        int c0 = cols[j], c1 = cols[j+1], c2 = cols[j+2], c3 = cols[j+3];
        float v0 = vals[j], v1 = vals[j+1], v2 = vals[j+2], v3 = vals[j+3];
        const float* p0 = (c0 < na) ? fa + (size_t)c0 * D : fb + (size_t)(c0 - na) * D;
        const float* p1 = (c1 < na) ? fa + (size_t)c1 * D : fb + (size_t)(c1 - na) * D;
        const float* p2 = (c2 < na) ? fa + (size_t)c2 * D : fb + (size_t)(c2 - na) * D;
        const float* p3 = (c3 < na) ? fa + (size_t)c3 * D : fb + (size_t)(c3 - na) * D;
        float4 x0 = *(const float4*)(p0 + t * 4);
        float4 x1 = *(const float4*)(p1 + t * 4);
        float4 x2 = *(const float4*)(p2 + t * 4);
        float4 x3 = *(const float4*)(p3 + t * 4);
        fma4(a0, v0, x0); fma4(a1, v1, x1); fma4(a2, v2, x2); fma4(a3, v3, x3);
    }
    for (; j < e; ++j) {
        int c0 = cols[j];
        float v0 = vals[j];
        const float* p0 = (c0 < na) ? fa + (size_t)c0 * D : fb + (size_t)(c0 - na) * D;
        float4 x0 = *(const float4*)(p0 + t * 4);
        fma4(a0, v0, x0);
    }
    a0.x += a1.x + a2.x + a3.x; a0.y += a1.y + a2.y + a3.y;
    a0.z += a1.z + a2.z + a3.z; a0.w += a1.w + a2.w + a3.w;
    *(float4*)(y1 + (size_t)r * D + t * 4) = a0;
}

// layer 2 fused with mean: acc[r] = (f[r] + y1[r] + sum_j val[j]*y1[col[j]]) / 3
__global__ __launch_bounds__(256) void k_spmm_l2(
    const int* __restrict__ rs, const int* __restrict__ cols,
    const float* __restrict__ vals, const float* __restrict__ y1,
    const float* __restrict__ fa, const float* __restrict__ fb, int na,
    float* __restrict__ acc, int N) {
    int r = blockIdx.x * 16 + (threadIdx.x >> 4);
    int t = threadIdx.x & 15;
    if (r >= N) return;
    int s = rs[r], e = rs[r + 1];
    float4 a0 = {0,0,0,0}, a1 = {0,0,0,0}, a2 = {0,0,0,0}, a3 = {0,0,0,0};
    int j = s;
    for (; j + 3 < e; j += 4) {
        int c0 = cols[j], c1 = cols[j+1], c2 = cols[j+2], c3 = cols[j+3];
        float v0 = vals[j], v1 = vals[j+1], v2 = vals[j+2], v3 = vals[j+3];
        float4 x0 = *(const float4*)(y1 + (size_t)c0 * D + t * 4);
        float4 x1 = *(const float4*)(y1 + (size_t)c1 * D + t * 4);
        float4 x2 = *(const float4*)(y1 + (size_t)c2 * D + t * 4);
        float4 x3 = *(const float4*)(y1 + (size_t)c3 * D + t * 4);
        fma4(a0, v0, x0); fma4(a1, v1, x1); fma4(a2, v2, x2); fma4(a3, v3, x3);
    }
    for (; j < e; ++j) {
        int c0 = cols[j];
        float v0 = vals[j];
        float4 x0 = *(const float4*)(y1 + (size_t)c0 * D + t * 4);
        fma4(a0, v0, x0);
    }
    const float* pf = (r < na) ? fa + (size_t)r * D : fb + (size_t)(r - na) * D;
    float4 f0 = *(const float4*)(pf + t * 4);
    float4 yv = *(const float4*)(y1 + (size_t)r * D + t * 4);
    constexpr float k3 = 1.0f / 3.0f;
    float4 o;
    o.x = (f0.x + yv.x + a0.x + a1.x + a2.x + a3.x) * k3;
    o.y = (f0.y + yv.y + a0.y + a1.y + a2.y + a3.y) * k3;
    o.z = (f0.z + yv.z + a0.z + a1.z + a2.z + a3.z) * k3;
    o.w = (f0.w + yv.w + a0.w + a1.w + a2.w + a3.w) * k3;
    *(float4*)(acc + (size_t)r * D + t * 4) = o;
}

// ---------------- scoring ----------------
// 256-thread block per candidate pair. CONSERVATIVE phase structure: every
// cross-phase value goes through LDS + __syncthreads(); softmax+top-k is
// R3's proven serial thread-0 code. No same-wave LDS RAW anywhere.
__global__ __launch_bounds__(256) void k_score(
    const int* __restrict__ users, const int* __restrict__ bundles,
    const int* __restrict__ bundle_items,
    const float* __restrict__ m_ub, const float* __restrict__ m_ui,
    const float* __restrict__ m_bi,
    const float* __restrict__ cw1, const float* __restrict__ cb1,
    const float* __restrict__ cw2, const float* __restrict__ cb2,
    const float* __restrict__ sw1, const float* __restrict__ sb1,
    const float* __restrict__ sw2, const float* __restrict__ sb2,
    float* __restrict__ scores) {
    const int n = blockIdx.x;
    const int t = threadIdx.x;      // 0..255
    const int ln = t & 63;          // lane within wave
    const int wv = t >> 6;          // wave 0..3
    const int g16 = t >> 4;         // group 0..15
    const int l16 = t & 15;         // lane within group
    const int u = users[n >> 1];
    const int b = bundles[n];

    __shared__ float s_items[MAXDEG][D];   // items_ui stash (50 KB)
    __shared__ float s_r[2][MAXDEG];
    __shared__ float s_pi[MAXDEG];
    __shared__ int   s_idx[MAXDEG];
    __shared__ int   s_top_i[CORE_K];
    __shared__ float s_top_p[CORE_K];
    __shared__ float s_syn[2 * D];
    __shared__ float s_part[4][D];
    __shared__ float s_h1[D];

    if (t < MAXDEG) s_idx[t] = bundle_items[(size_t)b * MAXDEG + t];
    __syncthreads();

    // this thread's 4-feature segment of the u / b rows
    const float4 u4 = *(const float4*)(m_ui + (size_t)u * D + l16 * 4);
    const float4 b4 = *(const float4*)(m_bi + (size_t)b * D + l16 * 4);

    // --- P1: 50 dual dot products, 16 items in flight (16 lanes x float4) ---
    for (int m = g16; m < MAXDEG; m += 16) {
        int it = s_idx[m];
        float4 iu = {0,0,0,0}, ib = {0,0,0,0};
        if (it != PAD_IDX) {
            iu = *(const float4*)(m_ui + (size_t)(NU + it) * D + l16 * 4);
            ib = *(const float4*)(m_bi + (size_t)(NB + it) * D + l16 * 4);
        }
        *(float4*)(&s_items[m][l16 * 4]) = iu;
        float pu = u4.x*iu.x + u4.y*iu.y + u4.z*iu.z + u4.w*iu.w;
        float pb = b4.x*ib.x + b4.y*ib.y + b4.z*ib.z + b4.w*ib.w;
#pragma unroll
        for (int off = 8; off > 0; off >>= 1) {
            pu += __shfl_down(pu, off, 16);
            pb += __shfl_down(pb, off, 16);
        }
        if (l16 == 0) { s_r[0][m] = pu; s_r[1][m] = pb; }
    }
    __syncthreads();

    // --- P2: core MLP (2->32->1) per item, threads 0..49; logits -> s_pi ---
    if (t < MAXDEG) {
        float rU = s_r[0][t], rB = s_r[1][t];
        float acc = cb2[0];
#pragma unroll
        for (int j = 0; j < 32; ++j) {
            float h = fmaf(rU, cw1[j], fmaf(rB, cw1[32 + j], cb1[j]));
            h = fmaxf(h, 0.f);
            acc = fmaf(h, cw2[j], acc);
        }
        s_pi[t] = (s_idx[t] != PAD_IDX) ? acc : -INFINITY;
    }
    __syncthreads();

    // --- P3 (thread 0, serial; R3-proven): softmax + top-3 ---
    if (t == 0) {
        float mx = -INFINITY;
        for (int m = 0; m < MAXDEG; ++m) mx = fmaxf(mx, s_pi[m]);
        float sm = 0.f;
        for (int m = 0; m < MAXDEG; ++m) {
            float e = expf(s_pi[m] - mx);
            s_pi[m] = e;
            sm += e;
        }
        float inv_sm = 1.f / sm;
        for (int m = 0; m < MAXDEG; ++m) s_pi[m] *= inv_sm;
        bool used[MAXDEG];
        for (int m = 0; m < MAXDEG; ++m) used[m] = false;
        float tsum = 0.f;
        for (int k = 0; k < CORE_K; ++k) {
            float best = -1.f; int bidx = 0;
            for (int m = 0; m < MAXDEG; ++m)
                if (!used[m] && s_pi[m] > best) { best = s_pi[m]; bidx = m; }
            used[bidx] = true;
            s_top_i[k] = bidx;
            s_top_p[k] = best;
            tsum += best;
        }
        float inv = 1.f / (tsum + 1e-10f);
        for (int k = 0; k < CORE_K; ++k) s_top_p[k] *= inv;
    }
    __syncthreads();

    // --- P4 (wave 0): h_core / h_fringe per feature dim ln ---
    if (wv == 0) {
        int ti0 = s_top_i[0], ti1 = s_top_i[1], ti2 = s_top_i[2];
        float hcore = s_items[ti0][ln] * s_top_p[0]
                    + s_items[ti1][ln] * s_top_p[1]
                    + s_items[ti2][ln] * s_top_p[2];
        float fsum = 0.f; int fcnt = 0;
        for (int m = 0; m < MAXDEG; ++m) {
            bool core = (m == ti0) | (m == ti1) | (m == ti2);
            if ((s_idx[m] != PAD_IDX) && !core) { fsum += s_items[m][ln]; fcnt++; }
        }
        float hfr = fsum / fmaxf((float)fcnt, 1.f);
        s_syn[ln] = hcore;
        s_syn[D + ln] = hfr;
    }
    __syncthreads();

    // --- P5: synergy MLP (128->64->64) split across 4 waves ---
    float h1p = 0.f;
    for (int k = 0; k < 32; ++k) {
        int kk = wv * 32 + k;
        h1p = fmaf(s_syn[kk], sw1[kk * D + ln], h1p);
    }
    s_part[wv][ln] = h1p;
    __syncthreads();
    if (t < D) {
        float h1 = sb1[t] + s_part[0][t] + s_part[1][t] + s_part[2][t] + s_part[3][t];
        s_h1[t] = fmaxf(h1, 0.f);
    }
    __syncthreads();
    float php = 0.f;
    for (int k = 0; k < 16; ++k) {
        int kk = wv * 16 + k;
        php = fmaf(s_h1[kk], sw2[kk * D + ln], php);
    }
    s_part[wv][ln] = php;
    __syncthreads();

    // --- P6 (wave 0): final score ---
    if (wv == 0) {
        float phi = sb2[ln] + s_part[0][ln] + s_part[1][ln] + s_part[2][ln] + s_part[3][ln];
        float hat = s_syn[ln] + phi;     // hcore + phi
        float uui = m_ui[(size_t)u * D + ln];
        float ubu = m_ub[(size_t)u * D + ln];
        float ubb = m_ub[(size_t)(NU + b) * D + ln];
        float part = wave_sum64(uui * ubb + ubu * hat);
        if (ln == 0) scores[n] = part;
    }
}

// mean over batch of softplus(neg - pos)
__global__ __launch_bounds__(256) void k_loss(const float* __restrict__ scores,
                                              float* __restrict__ out) {
    __shared__ float red[256];
    float s = 0.f;
    for (int i = threadIdx.x; i < BATCH; i += 256) {
        float x = scores[i * 2 + 1] - scores[i * 2 + 0];
        s += fmaxf(x, 0.f) + log1pf(expf(-fabsf(x)));
    }
    red[threadIdx.x] = s;
    __syncthreads();
    for (int w = 128; w > 0; w >>= 1) {
        if (threadIdx.x < w) red[threadIdx.x] += red[threadIdx.x + w];
        __syncthreads();
    }
    if (threadIdx.x == 0) out[0] = red[0] / (float)BATCH;
}

extern "C" void kernel_launch(void* const* d_in, const int* in_sizes, int n_in,
                              void* d_out, int out_size, void* d_ws, size_t ws_size,
                              hipStream_t stream) {
    const float* users_feature   = (const float*)d_in[0];
    const float* bundles_feature = (const float*)d_in[1];
    const float* items_feature   = (const float*)d_in[2];
    const float* cw1 = (const float*)d_in[3];
    const float* cb1 = (const float*)d_in[4];
    const float* cw2 = (const float*)d_in[5];
    const float* cb2 = (const float*)d_in[6];
    const float* sw1 = (const float*)d_in[7];
    const float* sb1 = (const float*)d_in[8];
    const float* sw2 = (const float*)d_in[9];
    const float* sb2 = (const float*)d_in[10];
    const float* ub_val = (const float*)d_in[11];
    const float* ui_val = (const float*)d_in[12];
    const float* bi_val = (const float*)d_in[13];
    const int* users   = (const int*)d_in[14];
    const int* bundles = (const int*)d_in[15];
    const int* ub_row = (const int*)d_in[16];
    const int* ub_col = (const int*)d_in[17];
    const int* ui_row = (const int*)d_in[18];
    const int* ui_col = (const int*)d_in[19];
    const int* bi_row = (const int*)d_in[20];
    const int* bi_col = (const int*)d_in[21];
    const int* bundle_items = (const int*)d_in[22];
    const int E_UB = in_sizes[11], E_UI = in_sizes[12], E_BI = in_sizes[13];
    const int E_TOT = E_UB + E_UI + E_BI;

    // workspace layout (4-byte elements), ~154 MB total
    float* ws = (float*)d_ws;
    size_t off = 0;
    float* acc    = ws + off; off += (size_t)N_TOT * D;   // combined reps, 87 MB
    float* y1buf  = ws + off; off += (size_t)N_UI * D;    // per-graph temp, 38.4 MB
    float* scores = ws + off; off += (size_t)BATCH * NCAND;
    int*   cnt    = (int*)(ws + off); off += N_TOT;
    int*   rstart = (int*)(ws + off); off += N_TOT + 1;
    int*   cursor = (int*)(ws + off); off += N_TOT;
    int*   bsum   = (int*)(ws + off); off += 512;
    int*   col_s  = (int*)(ws + off); off += E_TOT;       // graph-local col ids
    float* val_s  = ws + off; off += E_TOT;
    if (ws_size < off * sizeof(float)) return;  // fail loudly (wrong answer)

    // ---- fused CSR build (once, combined 340K-node space) ----
    hipMemsetAsync(cnt, 0, (size_t)N_TOT * sizeof(int), stream);
    k_hist3<<<(E_TOT + 255) / 256, 256, 0, stream>>>(ub_row, ui_row, bi_row,
                                                     E_UB, E_UI, E_BI, cnt);
    int nb = (N_TOT + SCAN_TILE - 1) / SCAN_TILE;   // 333
    k_scan1<<<nb, 256, 0, stream>>>(cnt, N_TOT, bsum);
    k_scan2<<<1, 64, 0, stream>>>(bsum, nb, rstart + N_TOT);
    k_scan3<<<nb, 256, 0, stream>>>(cnt, N_TOT, bsum, rstart, cursor);
    k_scatter3<<<(E_TOT + 255) / 256, 256, 0, stream>>>(
        ub_row, ub_col, ub_val, ui_row, ui_col, ui_val, bi_row, bi_col, bi_val,
        E_UB, E_UI, E_BI, cursor, col_s, val_s);

    // ---- per-graph propagation (rs offsets index the combined edge arrays) --
    auto propagate = [&](int row_off, int n, const float* fa, int na,
                         const float* fb) {
        const int* rs = rstart + row_off;
        float* accg = acc + (size_t)row_off * D;
        int sb = (n + 15) / 16;
        k_spmm_l1<<<sb, 256, 0, stream>>>(rs, col_s, val_s, fa, fb, na, y1buf, n);
        k_spmm_l2<<<sb, 256, 0, stream>>>(rs, col_s, val_s, y1buf, fa, fb, na,
                                          accg, n);
    };
    propagate(0,    N_UB, users_feature,   NU, bundles_feature);
    propagate(OFF1, N_UI, users_feature,   NU, items_feature);
    propagate(OFF2, N_BI, bundles_feature, NB, items_feature);

    k_score<<<BATCH * NCAND, 256, 0, stream>>>(
        users, bundles, bundle_items,
        acc, acc + (size_t)OFF1 * D, acc + (size_t)OFF2 * D,
        cw1, cb1, cw2, cb2, sw1, sb1, sw2, sb2, scores);

    k_loss<<<1, 256, 0, stream>>>(scores, (float*)d_out);
}

// Round 7
// 797.022 us; speedup vs baseline: 6.8631x; 1.0489x over previous
//
#include <hip/hip_runtime.h>
#include <math.h>

// Problem constants (from reference)
constexpr int D = 64;
constexpr int NU = 50000, NB = 20000, NI = 100000;
constexpr int BATCH = 2048, NCAND = 2, MAXDEG = 50, CORE_K = 3;
constexpr int PAD_IDX = NI;
constexpr int N_UB = NU + NB, N_UI = NU + NI, N_BI = NB + NI;
constexpr int N_TOT = N_UB + N_UI + N_BI;   // 340000 combined node space
constexpr int OFF1 = N_UB;                  // UI node base
constexpr int OFF2 = N_UB + N_UI;           // BI node base
constexpr int SCAN_TILE = 1024;             // elems per scan block (256 thr x 4)

__device__ __forceinline__ float wave_sum64(float v) {
#pragma unroll
    for (int off = 32; off > 0; off >>= 1) v += __shfl_down(v, off);
    return v;  // valid in lane 0
}

// NOTE: function, not macro — a macro param named `x` would capture the `.x`
// member token in the body (R4 compile failure).
__device__ __forceinline__ void fma4(float4& a, float v, const float4& u) {
    a.x = fmaf(v, u.x, a.x); a.y = fmaf(v, u.y, a.y);
    a.z = fmaf(v, u.z, a.z); a.w = fmaf(v, u.w, a.w);
}

// ---------------- fused CSR build over combined node space ----------------

__global__ void k_hist3(const int* __restrict__ r0, const int* __restrict__ r1,
                        const int* __restrict__ r2, int e0, int e1, int e2,
                        int* __restrict__ cnt) {
    int i = blockIdx.x * blockDim.x + threadIdx.x;
    if (i >= e0 + e1 + e2) return;
    int r;
    if (i < e0) r = r0[i];
    else if (i < e0 + e1) r = r1[i - e0] + OFF1;
    else r = r2[i - e0 - e1] + OFF2;
    atomicAdd(&cnt[r], 1);
}

// per-block partial sums of cnt tiles (tile = 1024, thread t owns 4 contiguous)
__global__ __launch_bounds__(256) void k_scan1(const int* __restrict__ cnt, int N,
                                               int* __restrict__ bsum) {
    __shared__ int red[256];
    int base = blockIdx.x * SCAN_TILE + threadIdx.x * 4;
    int s = 0;
#pragma unroll
    for (int k = 0; k < 4; ++k) { int i = base + k; if (i < N) s += cnt[i]; }
    red[threadIdx.x] = s;
    __syncthreads();
    for (int w = 128; w > 0; w >>= 1) {
        if (threadIdx.x < w) red[threadIdx.x] += red[threadIdx.x + w];
        __syncthreads();
    }
    if (threadIdx.x == 0) bsum[blockIdx.x] = red[0];
}

// single-thread exclusive scan of block sums (R3-proven serial version);
// also writes rs[N] = total
__global__ void k_scan2(int* __restrict__ bsum, int nb, int* __restrict__ rs_total) {
    if (threadIdx.x == 0) {
        int run = 0;
        for (int i = 0; i < nb; ++i) { int t = bsum[i]; bsum[i] = run; run += t; }
        *rs_total = run;   // == E_tot
    }
}

// per-block exclusive scan of tile, + scanned block offset -> row_start & cursor
__global__ __launch_bounds__(256) void k_scan3(const int* __restrict__ cnt, int N,
                                               const int* __restrict__ bsum,
                                               int* __restrict__ rs,
                                               int* __restrict__ cursor) {
    __shared__ int s_ts[256];
    int t = threadIdx.x;
    int base = blockIdx.x * SCAN_TILE + t * 4;
    int v[4];
#pragma unroll
    for (int k = 0; k < 4; ++k) { int i = base + k; v[k] = (i < N) ? cnt[i] : 0; }
    int ts = v[0] + v[1] + v[2] + v[3];
    s_ts[t] = ts;
    __syncthreads();
    for (int off = 1; off < 256; off <<= 1) {
        int add = (t >= off) ? s_ts[t - off] : 0;
        __syncthreads();
        s_ts[t] += add;
        __syncthreads();
    }
    int pre = bsum[blockIdx.x] + (s_ts[t] - ts);
#pragma unroll
    for (int k = 0; k < 4; ++k) {
        int i = base + k;
        if (i < N) { rs[i] = pre; cursor[i] = pre; }
        pre += v[k];
    }
}

// scatter all three edge lists; (col,val) PACKED into one int2 -> single 8B
// store per edge (R6: two 4B stores to two arrays = 2 cache-line touches,
// WRITE_SIZE 306 MB). cols stored GRAPH-LOCAL.
__global__ void k_scatter3(const int* __restrict__ r0, const int* __restrict__ c0,
                           const float* __restrict__ v0,
                           const int* __restrict__ r1, const int* __restrict__ c1,
                           const float* __restrict__ v1,
                           const int* __restrict__ r2, const int* __restrict__ c2,
                           const float* __restrict__ v2,
                           int e0, int e1, int e2,
                           int* __restrict__ cursor,
                           int2* __restrict__ cv_s) {
    int i = blockIdx.x * blockDim.x + threadIdx.x;
    if (i >= e0 + e1 + e2) return;
    int r, c; float v;
    if (i < e0)            { r = r0[i];          c = c0[i];          v = v0[i]; }
    else if (i < e0 + e1)  { int k = i - e0;      r = r1[k] + OFF1;   c = c1[k]; v = v1[k]; }
    else                   { int k = i - e0 - e1; r = r2[k] + OFF2;   c = c2[k]; v = v2[k]; }
    int p = atomicAdd(&cursor[r], 1);
    cv_s[p] = make_int2(c, __float_as_int(v));
}

// ---------------- propagate (CSR gather, 16 lanes x float4 per row) --------

// layer 1: y1[r] = sum_j val[j] * f[col[j]]  where f = concat(fa, fb), cols local
__global__ __launch_bounds__(256) void k_spmm_l1(
    const int* __restrict__ rs, const int2* __restrict__ cv,
    const float* __restrict__ fa, const float* __restrict__ fb, int na,
    float* __restrict__ y1, int N) {
    int r = blockIdx.x * 16 + (threadIdx.x >> 4);
    int t = threadIdx.x & 15;
    if (r >= N) return;
    int s = rs[r], e = rs[r + 1];
    float4 a0 = {0,0,0,0}, a1 = {0,0,0,0}, a2 = {0,0,0,0}, a3 = {0,0,0,0};
    int j = s;
    for (; j + 3 < e; j += 4) {
        int2 q0 = cv[j], q1 = cv[j+1], q2 = cv[j+2], q3 = cv[j+3];
        int c0 = q0.x, c1 = q1.x, c2 = q2.x, c3 = q3.x;
        float v0 = __int_as_float(q0.y), v1 = __int_as_float(q1.y);
        float v2 = __int_as_float(q2.y), v3 = __int_as_float(q3.y);
        const float* p0 = (c0 < na) ? fa + (size_t)c0 * D : fb + (size_t)(c0 - na) * D;
        const float* p1 = (c1 < na) ? fa + (size_t)c1 * D : fb + (size_t)(c1 - na) * D;
        const float* p2 = (c2 < na) ? fa + (size_t)c2 * D : fb + (size_t)(c2 - na) * D;
        const float* p3 = (c3 < na) ? fa + (size_t)c3 * D : fb + (size_t)(c3 - na) * D;
        float4 x0 = *(const float4*)(p0 + t * 4);
        float4 x1 = *(const float4*)(p1 + t * 4);
        float4 x2 = *(const float4*)(p2 + t * 4);
        float4 x3 = *(const float4*)(p3 + t * 4);
        fma4(a0, v0, x0); fma4(a1, v1, x1); fma4(a2, v2, x2); fma4(a3, v3, x3);
    }
    for (; j < e; ++j) {
        int2 q0 = cv[j];
        int c0 = q0.x;
        float v0 = __int_as_float(q0.y);
        const float* p0 = (c0 < na) ? fa + (size_t)c0 * D : fb + (size_t)(c0 - na) * D;
        float4 x0 = *(const float4*)(p0 + t * 4);
        fma4(a0, v0, x0);
    }
    a0.x += a1.x + a2.x + a3.x; a0.y += a1.y + a2.y + a3.y;
    a0.z += a1.z + a2.z + a3.z; a0.w += a1.w + a2.w + a3.w;
    *(float4*)(y1 + (size_t)r * D + t * 4) = a0;
}

// layer 2 fused with mean: acc[r] = (f[r] + y1[r] + sum_j val[j]*y1[col[j]]) / 3
__global__ __launch_bounds__(256) void k_spmm_l2(
    const int* __restrict__ rs, const int2* __restrict__ cv,
    const float* __restrict__ y1,
    const float* __restrict__ fa, const float* __restrict__ fb, int na,
    float* __restrict__ acc, int N) {
    int r = blockIdx.x * 16 + (threadIdx.x >> 4);
    int t = threadIdx.x & 15;
    if (r >= N) return;
    int s = rs[r], e = rs[r + 1];
    float4 a0 = {0,0,0,0}, a1 = {0,0,0,0}, a2 = {0,0,0,0}, a3 = {0,0,0,0};
    int j = s;
    for (; j + 3 < e; j += 4) {
        int2 q0 = cv[j], q1 = cv[j+1], q2 = cv[j+2], q3 = cv[j+3];
        float v0 = __int_as_float(q0.y), v1 = __int_as_float(q1.y);
        float v2 = __int_as_float(q2.y), v3 = __int_as_float(q3.y);
        float4 x0 = *(const float4*)(y1 + (size_t)q0.x * D + t * 4);
        float4 x1 = *(const float4*)(y1 + (size_t)q1.x * D + t * 4);
        float4 x2 = *(const float4*)(y1 + (size_t)q2.x * D + t * 4);
        float4 x3 = *(const float4*)(y1 + (size_t)q3.x * D + t * 4);
        fma4(a0, v0, x0); fma4(a1, v1, x1); fma4(a2, v2, x2); fma4(a3, v3, x3);
    }
    for (; j < e; ++j) {
        int2 q0 = cv[j];
        float v0 = __int_as_float(q0.y);
        float4 x0 = *(const float4*)(y1 + (size_t)q0.x * D + t * 4);
        fma4(a0, v0, x0);
    }
    const float* pf = (r < na) ? fa + (size_t)r * D : fb + (size_t)(r - na) * D;
    float4 f0 = *(const float4*)(pf + t * 4);
    float4 yv = *(const float4*)(y1 + (size_t)r * D + t * 4);
    constexpr float k3 = 1.0f / 3.0f;
    float4 o;
    o.x = (f0.x + yv.x + a0.x + a1.x + a2.x + a3.x) * k3;
    o.y = (f0.y + yv.y + a0.y + a1.y + a2.y + a3.y) * k3;
    o.z = (f0.z + yv.z + a0.z + a1.z + a2.z + a3.z) * k3;
    o.w = (f0.w + yv.w + a0.w + a1.w + a2.w + a3.w) * k3;
    *(float4*)(acc + (size_t)r * D + t * 4) = o;
}

// ---------------- scoring ----------------
// 256-thread block per candidate pair. CONSERVATIVE phase structure: every
// cross-phase value goes through LDS + __syncthreads(); softmax+top-k is
// R3's proven serial thread-0 code. No same-wave LDS RAW anywhere.
__global__ __launch_bounds__(256) void k_score(
    const int* __restrict__ users, const int* __restrict__ bundles,
    const int* __restrict__ bundle_items,
    const float* __restrict__ m_ub, const float* __restrict__ m_ui,
    const float* __restrict__ m_bi,
    const float* __restrict__ cw1, const float* __restrict__ cb1,
    const float* __restrict__ cw2, const float* __restrict__ cb2,
    const float* __restrict__ sw1, const float* __restrict__ sb1,
    const float* __restrict__ sw2, const float* __restrict__ sb2,
    float* __restrict__ scores) {
    const int n = blockIdx.x;
    const int t = threadIdx.x;      // 0..255
    const int ln = t & 63;          // lane within wave
    const int wv = t >> 6;          // wave 0..3
    const int g16 = t >> 4;         // group 0..15
    const int l16 = t & 15;         // lane within group
    const int u = users[n >> 1];
    const int b = bundles[n];

    __shared__ float s_items[MAXDEG][D];   // items_ui stash (12.8 KB)
    __shared__ float s_r[2][MAXDEG];
    __shared__ float s_pi[MAXDEG];
    __shared__ int   s_idx[MAXDEG];
    __shared__ int   s_top_i[CORE_K];
    __shared__ float s_top_p[CORE_K];
    __shared__ float s_syn[2 * D];
    __shared__ float s_part[4][D];
    __shared__ float s_h1[D];

    if (t < MAXDEG) s_idx[t] = bundle_items[(size_t)b * MAXDEG + t];
    __syncthreads();

    // this thread's 4-feature segment of the u / b rows
    const float4 u4 = *(const float4*)(m_ui + (size_t)u * D + l16 * 4);
    const float4 b4 = *(const float4*)(m_bi + (size_t)b * D + l16 * 4);

    // --- P1: 50 dual dot products, 16 items in flight (16 lanes x float4) ---
    for (int m = g16; m < MAXDEG; m += 16) {
        int it = s_idx[m];
        float4 iu = {0,0,0,0}, ib = {0,0,0,0};
        if (it != PAD_IDX) {
            iu = *(const float4*)(m_ui + (size_t)(NU + it) * D + l16 * 4);
            ib = *(const float4*)(m_bi + (size_t)(NB + it) * D + l16 * 4);
        }
        *(float4*)(&s_items[m][l16 * 4]) = iu;
        float pu = u4.x*iu.x + u4.y*iu.y + u4.z*iu.z + u4.w*iu.w;
        float pb = b4.x*ib.x + b4.y*ib.y + b4.z*ib.z + b4.w*ib.w;
#pragma unroll
        for (int off = 8; off > 0; off >>= 1) {
            pu += __shfl_down(pu, off, 16);
            pb += __shfl_down(pb, off, 16);
        }
        if (l16 == 0) { s_r[0][m] = pu; s_r[1][m] = pb; }
    }
    __syncthreads();

    // --- P2: core MLP (2->32->1) per item, threads 0..49; logits -> s_pi ---
    if (t < MAXDEG) {
        float rU = s_r[0][t], rB = s_r[1][t];
        float acc = cb2[0];
#pragma unroll
        for (int j = 0; j < 32; ++j) {
            float h = fmaf(rU, cw1[j], fmaf(rB, cw1[32 + j], cb1[j]));
            h = fmaxf(h, 0.f);
            acc = fmaf(h, cw2[j], acc);
        }
        s_pi[t] = (s_idx[t] != PAD_IDX) ? acc : -INFINITY;
    }
    __syncthreads();

    // --- P3 (thread 0, serial; R3-proven): softmax + top-3 ---
    if (t == 0) {
        float mx = -INFINITY;
        for (int m = 0; m < MAXDEG; ++m) mx = fmaxf(mx, s_pi[m]);
        float sm = 0.f;
        for (int m = 0; m < MAXDEG; ++m) {
            float e = expf(s_pi[m] - mx);
            s_pi[m] = e;
            sm += e;
        }
        float inv_sm = 1.f / sm;
        for (int m = 0; m < MAXDEG; ++m) s_pi[m] *= inv_sm;
        bool used[MAXDEG];
        for (int m = 0; m < MAXDEG; ++m) used[m] = false;
        float tsum = 0.f;
        for (int k = 0; k < CORE_K; ++k) {
            float best = -1.f; int bidx = 0;
            for (int m = 0; m < MAXDEG; ++m)
                if (!used[m] && s_pi[m] > best) { best = s_pi[m]; bidx = m; }
            used[bidx] = true;
            s_top_i[k] = bidx;
            s_top_p[k] = best;
            tsum += best;
        }
        float inv = 1.f / (tsum + 1e-10f);
        for (int k = 0; k < CORE_K; ++k) s_top_p[k] *= inv;
    }
    __syncthreads();

    // --- P4 (wave 0): h_core / h_fringe per feature dim ln ---
    if (wv == 0) {
        int ti0 = s_top_i[0], ti1 = s_top_i[1], ti2 = s_top_i[2];
        float hcore = s_items[ti0][ln] * s_top_p[0]
                    + s_items[ti1][ln] * s_top_p[1]
                    + s_items[ti2][ln] * s_top_p[2];
        float fsum = 0.f; int fcnt = 0;
        for (int m = 0; m < MAXDEG; ++m) {
            bool core = (m == ti0) | (m == ti1) | (m == ti2);
            if ((s_idx[m] != PAD_IDX) && !core) { fsum += s_items[m][ln]; fcnt++; }
        }
        float hfr = fsum / fmaxf((float)fcnt, 1.f);
        s_syn[ln] = hcore;
        s_syn[D + ln] = hfr;
    }
    __syncthreads();

    // --- P5: synergy MLP (128->64->64) split across 4 waves ---
    float h1p = 0.f;
    for (int k = 0; k < 32; ++k) {
        int kk = wv * 32 + k;
        h1p = fmaf(s_syn[kk], sw1[kk * D + ln], h1p);
    }
    s_part[wv][ln] = h1p;
    __syncthreads();
    if (t < D) {
        float h1 = sb1[t] + s_part[0][t] + s_part[1][t] + s_part[2][t] + s_part[3][t];
        s_h1[t] = fmaxf(h1, 0.f);
    }
    __syncthreads();
    float php = 0.f;
    for (int k = 0; k < 16; ++k) {
        int kk = wv * 16 + k;
        php = fmaf(s_h1[kk], sw2[kk * D + ln], php);
    }
    s_part[wv][ln] = php;
    __syncthreads();

    // --- P6 (wave 0): final score ---
    if (wv == 0) {
        float phi = sb2[ln] + s_part[0][ln] + s_part[1][ln] + s_part[2][ln] + s_part[3][ln];
        float hat = s_syn[ln] + phi;     // hcore + phi
        float uui = m_ui[(size_t)u * D + ln];
        float ubu = m_ub[(size_t)u * D + ln];
        float ubb = m_ub[(size_t)(NU + b) * D + ln];
        float part = wave_sum64(uui * ubb + ubu * hat);
        if (ln == 0) scores[n] = part;
    }
}

// mean over batch of softplus(neg - pos)
__global__ __launch_bounds__(256) void k_loss(const float* __restrict__ scores,
                                              float* __restrict__ out) {
    __shared__ float red[256];
    float s = 0.f;
    for (int i = threadIdx.x; i < BATCH; i += 256) {
        float x = scores[i * 2 + 1] - scores[i * 2 + 0];
        s += fmaxf(x, 0.f) + log1pf(expf(-fabsf(x)));
    }
    red[threadIdx.x] = s;
    __syncthreads();
    for (int w = 128; w > 0; w >>= 1) {
        if (threadIdx.x < w) red[threadIdx.x] += red[threadIdx.x + w];
        __syncthreads();
    }
    if (threadIdx.x == 0) out[0] = red[0] / (float)BATCH;
}

extern "C" void kernel_launch(void* const* d_in, const int* in_sizes, int n_in,
                              void* d_out, int out_size, void* d_ws, size_t ws_size,
                              hipStream_t stream) {
    const float* users_feature   = (const float*)d_in[0];
    const float* bundles_feature = (const float*)d_in[1];
    const float* items_feature   = (const float*)d_in[2];
    const float* cw1 = (const float*)d_in[3];
    const float* cb1 = (const float*)d_in[4];
    const float* cw2 = (const float*)d_in[5];
    const float* cb2 = (const float*)d_in[6];
    const float* sw1 = (const float*)d_in[7];
    const float* sb1 = (const float*)d_in[8];
    const float* sw2 = (const float*)d_in[9];
    const float* sb2 = (const float*)d_in[10];
    const float* ub_val = (const float*)d_in[11];
    const float* ui_val = (const float*)d_in[12];
    const float* bi_val = (const float*)d_in[13];
    const int* users   = (const int*)d_in[14];
    const int* bundles = (const int*)d_in[15];
    const int* ub_row = (const int*)d_in[16];
    const int* ub_col = (const int*)d_in[17];
    const int* ui_row = (const int*)d_in[18];
    const int* ui_col = (const int*)d_in[19];
    const int* bi_row = (const int*)d_in[20];
    const int* bi_col = (const int*)d_in[21];
    const int* bundle_items = (const int*)d_in[22];
    const int E_UB = in_sizes[11], E_UI = in_sizes[12], E_BI = in_sizes[13];
    const int E_TOT = E_UB + E_UI + E_BI;

    // workspace layout (4-byte elements), ~154 MB total.
    // cv_s (int2) must be 8B-aligned: all preceding sizes kept even.
    float* ws = (float*)d_ws;
    size_t off = 0;
    float* acc    = ws + off; off += (size_t)N_TOT * D;   // combined reps, 87 MB
    float* y1buf  = ws + off; off += (size_t)N_UI * D;    // per-graph temp, 38.4 MB
    float* scores = ws + off; off += (size_t)BATCH * NCAND;
    int*   cnt    = (int*)(ws + off); off += N_TOT;
    int*   rstart = (int*)(ws + off); off += N_TOT + 2;   // +2 keeps 8B alignment
    int*   cursor = (int*)(ws + off); off += N_TOT;
    int*   bsum   = (int*)(ws + off); off += 512;
    int2*  cv_s   = (int2*)(ws + off); off += (size_t)E_TOT * 2;  // packed (col,val)
    if (ws_size < off * sizeof(float)) return;  // fail loudly (wrong answer)

    // ---- fused CSR build (once, combined 340K-node space) ----
    hipMemsetAsync(cnt, 0, (size_t)N_TOT * sizeof(int), stream);
    k_hist3<<<(E_TOT + 255) / 256, 256, 0, stream>>>(ub_row, ui_row, bi_row,
                                                     E_UB, E_UI, E_BI, cnt);
    int nb = (N_TOT + SCAN_TILE - 1) / SCAN_TILE;   // 333
    k_scan1<<<nb, 256, 0, stream>>>(cnt, N_TOT, bsum);
    k_scan2<<<1, 64, 0, stream>>>(bsum, nb, rstart + N_TOT);
    k_scan3<<<nb, 256, 0, stream>>>(cnt, N_TOT, bsum, rstart, cursor);
    k_scatter3<<<(E_TOT + 255) / 256, 256, 0, stream>>>(
        ub_row, ub_col, ub_val, ui_row, ui_col, ui_val, bi_row, bi_col, bi_val,
        E_UB, E_UI, E_BI, cursor, cv_s);

    // ---- per-graph propagation (rs offsets index the combined edge array) --
    auto propagate = [&](int row_off, int n, const float* fa, int na,
                         const float* fb) {
        const int* rs = rstart + row_off;
        float* accg = acc + (size_t)row_off * D;
        int sb = (n + 15) / 16;
        k_spmm_l1<<<sb, 256, 0, stream>>>(rs, cv_s, fa, fb, na, y1buf, n);
        k_spmm_l2<<<sb, 256, 0, stream>>>(rs, cv_s, y1buf, fa, fb, na, accg, n);
    };
    propagate(0,    N_UB, users_feature,   NU, bundles_feature);
    propagate(OFF1, N_UI, users_feature,   NU, items_feature);
    propagate(OFF2, N_BI, bundles_feature, NB, items_feature);

    k_score<<<BATCH * NCAND, 256, 0, stream>>>(
        users, bundles, bundle_items,
        acc, acc + (size_t)OFF1 * D, acc + (size_t)OFF2 * D,
        cw1, cb1, cw2, cb2, sw1, sb1, sw2, sb2, scores);

    k_loss<<<1, 256, 0, stream>>>(scores, (float*)d_out);
}